// Round 4
// baseline (100.379 us; speedup 1.0000x reference)
//
#include <hip/hip_runtime.h>
#include <math.h>

// Problem constants: S1 = S2 = 4096, D = 64, H = 2, KD = VD = 1.
// Rank-1 attention: attn[h,s,t] = q[s,h]*k[t,h] -> only row sums of exp needed.
#define NS 4096
#define LOG2E 1.44269504088896f

// Workspace layout (float offsets)
static constexpr int OFF_SUMX1 = 0;             // 64 (zeroed)
static constexpr int OFF_SUMX2 = 64;            // 64 (zeroed)
static constexpr int OFF_SSQX2 = 128;           // 64 (zeroed)
static constexpr int OFF_Q     = 256;           // q0[4096], q1[4096]
static constexpr int OFF_KV    = 256 + 2*4096;  // float4 kv[4096] = (k0,k1,v0,v1); byte 33792, 16B-aligned

__device__ inline float wred64(float v) {
    #pragma unroll
    for (int off = 32; off; off >>= 1) v += __shfl_xor(v, off);
    return v;
}

// K1: column sums of x1, column sums + sumsq of x2.
// 256 blocks x 256 threads. Blocks 0..127 -> x1 (32 rows each), 128..255 -> x2.
__global__ __launch_bounds__(256) void k_colred(const float* __restrict__ x1,
                                                const float* __restrict__ x2,
                                                float* __restrict__ ws) {
    int b = blockIdx.x;
    int tid = threadIdx.x;
    int w = tid >> 6, d = tid & 63;
    bool isx2 = (b >= 128);
    const float* x = isx2 ? x2 : x1;
    int row0 = (isx2 ? (b - 128) : b) * 32 + w * 8;
    float s = 0.f, ss = 0.f;
    #pragma unroll
    for (int i = 0; i < 8; ++i) {
        float v = x[(row0 + i) * 64 + d];
        s += v; ss += v * v;
    }
    __shared__ float redS[256];
    __shared__ float redQ[256];
    redS[tid] = s; redQ[tid] = ss;
    __syncthreads();
    if (tid < 64) {
        float st = redS[tid] + redS[tid + 64] + redS[tid + 128] + redS[tid + 192];
        if (!isx2) {
            atomicAdd(&ws[OFF_SUMX1 + tid], st);
        } else {
            float sq = redQ[tid] + redQ[tid + 64] + redQ[tid + 128] + redQ[tid + 192];
            atomicAdd(&ws[OFF_SUMX2 + tid], st);
            atomicAdd(&ws[OFF_SSQX2 + tid], sq);
        }
    }
}

// K2: fused prep + projections. 512 blocks x 256 threads, 16 rows/block.
// Blocks 0..255: x2 rows -> redundant CBN prep (scale/beta/mu in LDS) + k,v.
// Blocks 256..511: x1 rows -> q (no prep dependency).
__global__ __launch_bounds__(256) void k_prep_proj(const float* __restrict__ x1,
                                                   const float* __restrict__ x2,
                                                   const float* __restrict__ Wq,
                                                   const float* __restrict__ Wk,
                                                   const float* __restrict__ Wv,
                                                   const float* __restrict__ Wg1,
                                                   const float* __restrict__ Wg2,
                                                   const float* __restrict__ Wb1,
                                                   const float* __restrict__ Wb2,
                                                   float* __restrict__ ws) {
    int b = blockIdx.x, tid = threadIdx.x;
    int w = tid >> 6, d = tid & 63;
    if (b < 256) {
        __shared__ float hsh[64], pg_[4][64], pb_[4][64], ag[64], ab[64];
        __shared__ float scl[64], bta[64], mu[64];
        if (tid < 64) hsh[tid] = ws[OFF_SUMX1 + tid] * (1.f / 4096.f);
        __syncthreads();
        // layer 1: j-range split across the 4 waves, reduce in LDS
        float pg = 0.f, pb = 0.f;
        #pragma unroll
        for (int jj = 0; jj < 16; ++jj) {
            int j = w * 16 + jj; float hj = hsh[j];
            pg = fmaf(hj, Wg1[j * 64 + d], pg);
            pb = fmaf(hj, Wb1[j * 64 + d], pb);
        }
        pg_[w][d] = pg; pb_[w][d] = pb;
        __syncthreads();
        if (w == 0) {
            ag[d] = fmaxf(pg_[0][d] + pg_[1][d] + pg_[2][d] + pg_[3][d], 0.f);
            ab[d] = fmaxf(pb_[0][d] + pb_[1][d] + pb_[2][d] + pb_[3][d], 0.f);
        }
        __syncthreads();
        // layer 2
        pg = 0.f; pb = 0.f;
        #pragma unroll
        for (int jj = 0; jj < 16; ++jj) {
            int j = w * 16 + jj;
            pg = fmaf(ag[j], Wg2[j * 64 + d], pg);
            pb = fmaf(ab[j], Wb2[j * 64 + d], pb);
        }
        pg_[w][d] = pg; pb_[w][d] = pb;
        __syncthreads();
        if (w == 0) {
            float dg = pg_[0][d] + pg_[1][d] + pg_[2][d] + pg_[3][d];
            float db = pb_[0][d] + pb_[1][d] + pb_[2][d] + pb_[3][d];
            float muv = ws[OFF_SUMX2 + d] * (1.f / 4096.f);
            float var = ws[OFF_SSQX2 + d] * (1.f / 4096.f) - muv * muv;
            scl[d] = (1.f + dg) * rsqrtf(var + 1e-5f);
            bta[d] = db; mu[d] = muv;
        }
        __syncthreads();
        float wk0 = Wk[d * 2 + 0], wk1 = Wk[d * 2 + 1];
        float wv0 = Wv[d * 2 + 0], wv1 = Wv[d * 2 + 1];
        float4* kvo = (float4*)(ws + OFF_KV);
        #pragma unroll
        for (int r = 0; r < 4; ++r) {
            int row = b * 16 + w * 4 + r;
            float x = x2[row * 64 + d];
            float n2 = wred64(x * x);
            float y = x * (1.f / fmaxf(sqrtf(n2), 1e-12f));            // y2 row
            float vv = fmaf(scl[d], x - mu[d], bta[d]);                // v2_0
            float nv = wred64(vv * vv);
            float vn = vv * (1.f / fmaxf(sqrtf(nv), 1e-12f));          // v2n
            float k0 = wred64(y * wk0),  k1 = wred64(y * wk1);
            float v0 = wred64(vn * wv0), v1 = wred64(vn * wv1);
            if (d == 0) kvo[row] = make_float4(k0, k1, v0, v1);
        }
    } else {
        float wq0 = Wq[d * 2 + 0], wq1 = Wq[d * 2 + 1];
        #pragma unroll
        for (int r = 0; r < 4; ++r) {
            int row = (b - 256) * 16 + w * 4 + r;
            float x = x1[row * 64 + d];
            float n2 = wred64(x * x);
            float y = x * (1.f / fmaxf(sqrtf(n2), 1e-12f));            // y1 row
            float q0 = wred64(y * wq0), q1 = wred64(y * wq1);
            if (d == 0) { ws[OFF_Q + row] = q0; ws[OFF_Q + 4096 + row] = q1; }
        }
    }
}

// K3: attention + output, no atomics. 512 blocks x 256 threads; block owns 8 s-rows,
// threads slice over t (16 coalesced float4 kv each), accumulate 8s x 2h in registers,
// wave shuffle-reduce + LDS cross-wave reduce, then sigmoid(o@Wo+bo) written directly.
__global__ __launch_bounds__(256) void k_attn_out(const float* __restrict__ ws,
                                                  const float* __restrict__ Wk,
                                                  const float* __restrict__ Wo,
                                                  const float* __restrict__ bo,
                                                  float* __restrict__ out) {
    int b = blockIdx.x, tid = threadIdx.x;
    int w = tid >> 6, lane = tid & 63;
    __shared__ float kb[2];
    __shared__ float qsh[2][8];
    if (w == 0) {   // ||Wk col|| bounds (analytic softmax shift; exps end up in [-2m,0])
        float c0 = Wk[lane * 2 + 0], c1 = Wk[lane * 2 + 1];
        float s0 = wred64(c0 * c0), s1 = wred64(c1 * c1);
        if (lane == 0) { kb[0] = sqrtf(s0); kb[1] = sqrtf(s1); }
    }
    if (tid >= 64 && tid < 72) {  // wave1 loads this block's 8 q-pairs
        int si = tid - 64;
        qsh[0][si] = ws[OFF_Q + b * 8 + si];
        qsh[1][si] = ws[OFF_Q + 4096 + b * 8 + si];
    }
    __syncthreads();
    float q0r[8], q1r[8], m0r[8], m1r[8];
    #pragma unroll
    for (int si = 0; si < 8; ++si) {   // pre-scale by log2(e): exp(x) = exp2(x*LOG2E)
        q0r[si] = qsh[0][si] * LOG2E;
        q1r[si] = qsh[1][si] * LOG2E;
        m0r[si] = fabsf(q0r[si]) * kb[0];
        m1r[si] = fabsf(q1r[si]) * kb[1];
    }
    float n0[8], d0[8], n1[8], d1[8];
    #pragma unroll
    for (int si = 0; si < 8; ++si) { n0[si] = 0.f; d0[si] = 0.f; n1[si] = 0.f; d1[si] = 0.f; }
    const float4* kvg = (const float4*)(ws + OFF_KV);
    for (int i = 0; i < 16; ++i) {
        float4 t = kvg[i * 256 + tid];
        #pragma unroll
        for (int si = 0; si < 8; ++si) {
            float e0 = exp2f(fmaf(q0r[si], t.x, -m0r[si]));
            n0[si] = fmaf(e0, t.z, n0[si]); d0[si] += e0;
            float e1 = exp2f(fmaf(q1r[si], t.y, -m1r[si]));
            n1[si] = fmaf(e1, t.w, n1[si]); d1[si] += e1;
        }
    }
    #pragma unroll
    for (int si = 0; si < 8; ++si) {
        n0[si] = wred64(n0[si]); d0[si] = wred64(d0[si]);
        n1[si] = wred64(n1[si]); d1[si] = wred64(d1[si]);
    }
    __shared__ float red[4][32];
    if (lane == 0) {
        #pragma unroll
        for (int si = 0; si < 8; ++si) {
            red[w][si]      = n0[si];
            red[w][8 + si]  = d0[si];
            red[w][16 + si] = n1[si];
            red[w][24 + si] = d1[si];
        }
    }
    __syncthreads();
    __shared__ float fin[32];
    if (tid < 32) fin[tid] = red[0][tid] + red[1][tid] + red[2][tid] + red[3][tid];
    __syncthreads();
    if (tid < 8) {
        float o0 = fin[tid]      / fin[8 + tid];
        float o1 = fin[16 + tid] / fin[24 + tid];
        float z0 = fmaf(o0, Wo[0], fmaf(o1, Wo[2], bo[0]));
        float z1 = fmaf(o0, Wo[1], fmaf(o1, Wo[3], bo[1]));
        int s = b * 8 + tid;
        out[s * 2 + 0] = 1.f / (1.f + __expf(-z0));
        out[s * 2 + 1] = 1.f / (1.f + __expf(-z1));
    }
}

extern "C" void kernel_launch(void* const* d_in, const int* in_sizes, int n_in,
                              void* d_out, int out_size, void* d_ws, size_t ws_size,
                              hipStream_t stream) {
    const float* x1  = (const float*)d_in[0];
    const float* x2  = (const float*)d_in[1];
    const float* Wq  = (const float*)d_in[2];
    const float* Wk  = (const float*)d_in[3];
    const float* Wv  = (const float*)d_in[4];
    const float* Wo  = (const float*)d_in[5];
    const float* bo  = (const float*)d_in[6];
    const float* Wg1 = (const float*)d_in[7];
    const float* Wg2 = (const float*)d_in[8];
    const float* Wb1 = (const float*)d_in[9];
    const float* Wb2 = (const float*)d_in[10];
    float* ws  = (float*)d_ws;
    float* out = (float*)d_out;

    // Zero only the 192-float atomic accumulation region (ws poisoned 0xAA).
    hipMemsetAsync(d_ws, 0, 192 * 4, stream);

    k_colred<<<256, 256, 0, stream>>>(x1, x2, ws);
    k_prep_proj<<<512, 256, 0, stream>>>(x1, x2, Wq, Wk, Wv, Wg1, Wg2, Wb1, Wb2, ws);
    k_attn_out<<<512, 256, 0, stream>>>(ws, Wk, Wo, bo, out);
}

// Round 6
// 99.665 us; speedup vs baseline: 1.0072x; 1.0072x over previous
//
#include <hip/hip_runtime.h>
#include <math.h>

// Problem constants: S1 = S2 = 4096, D = 64, H = 2, KD = VD = 1.
// Rank-1 attention: attn[h,s,t] = q[s,h]*k[t,h] -> only row sums of exp needed.
#define NS 4096
#define LOG2E 1.44269504088896f

// Workspace layout (float offsets)
static constexpr int OFF_SUMX1 = 0;             // 64 (zeroed)
static constexpr int OFF_SUMX2 = 64;            // 64 (zeroed)
static constexpr int OFF_SSQX2 = 128;           // 64 (zeroed)
static constexpr int OFF_Q     = 256;           // q0[4096], q1[4096]
static constexpr int OFF_KV    = 256 + 2*4096;  // float4 kv[4096] = (k0,k1,v0,v1); byte 33792, 16B-aligned

__device__ inline float wred64(float v) {
    #pragma unroll
    for (int off = 32; off; off >>= 1) v += __shfl_xor(v, off);
    return v;
}

// K1: column sums of x1, column sums + sumsq of x2.
// 256 blocks x 256 threads. Blocks 0..127 -> x1 (32 rows each), 128..255 -> x2.
__global__ __launch_bounds__(256) void k_colred(const float* __restrict__ x1,
                                                const float* __restrict__ x2,
                                                float* __restrict__ ws) {
    int b = blockIdx.x;
    int tid = threadIdx.x;
    int w = tid >> 6, d = tid & 63;
    bool isx2 = (b >= 128);
    const float* x = isx2 ? x2 : x1;
    int row0 = (isx2 ? (b - 128) : b) * 32 + w * 8;
    float s = 0.f, ss = 0.f;
    #pragma unroll
    for (int i = 0; i < 8; ++i) {
        float v = x[(row0 + i) * 64 + d];
        s += v; ss += v * v;
    }
    __shared__ float redS[256];
    __shared__ float redQ[256];
    redS[tid] = s; redQ[tid] = ss;
    __syncthreads();
    if (tid < 64) {
        float st = redS[tid] + redS[tid + 64] + redS[tid + 128] + redS[tid + 192];
        if (!isx2) {
            atomicAdd(&ws[OFF_SUMX1 + tid], st);
        } else {
            float sq = redQ[tid] + redQ[tid + 64] + redQ[tid + 128] + redQ[tid + 192];
            atomicAdd(&ws[OFF_SUMX2 + tid], st);
            atomicAdd(&ws[OFF_SSQX2 + tid], sq);
        }
    }
}

// K2: fused prep + projections. 512 blocks x 256 threads, 16 rows/block.
// Blocks 0..255: x2 rows -> redundant CBN prep (scale/beta/mu in LDS) + k,v.
// Blocks 256..511: x1 rows -> q (no prep dependency).
__global__ __launch_bounds__(256) void k_prep_proj(const float* __restrict__ x1,
                                                   const float* __restrict__ x2,
                                                   const float* __restrict__ Wq,
                                                   const float* __restrict__ Wk,
                                                   const float* __restrict__ Wv,
                                                   const float* __restrict__ Wg1,
                                                   const float* __restrict__ Wg2,
                                                   const float* __restrict__ Wb1,
                                                   const float* __restrict__ Wb2,
                                                   float* __restrict__ ws) {
    int b = blockIdx.x, tid = threadIdx.x;
    int w = tid >> 6, d = tid & 63;
    if (b < 256) {
        __shared__ float hsh[64], pg_[4][64], pb_[4][64], ag[64], ab[64];
        __shared__ float scl[64], bta[64], mu[64];
        if (tid < 64) hsh[tid] = ws[OFF_SUMX1 + tid] * (1.f / 4096.f);
        __syncthreads();
        // layer 1: j-range split across the 4 waves, reduce in LDS
        float pg = 0.f, pb = 0.f;
        #pragma unroll
        for (int jj = 0; jj < 16; ++jj) {
            int j = w * 16 + jj; float hj = hsh[j];
            pg = fmaf(hj, Wg1[j * 64 + d], pg);
            pb = fmaf(hj, Wb1[j * 64 + d], pb);
        }
        pg_[w][d] = pg; pb_[w][d] = pb;
        __syncthreads();
        if (w == 0) {
            ag[d] = fmaxf(pg_[0][d] + pg_[1][d] + pg_[2][d] + pg_[3][d], 0.f);
            ab[d] = fmaxf(pb_[0][d] + pb_[1][d] + pb_[2][d] + pb_[3][d], 0.f);
        }
        __syncthreads();
        // layer 2
        pg = 0.f; pb = 0.f;
        #pragma unroll
        for (int jj = 0; jj < 16; ++jj) {
            int j = w * 16 + jj;
            pg = fmaf(ag[j], Wg2[j * 64 + d], pg);
            pb = fmaf(ab[j], Wb2[j * 64 + d], pb);
        }
        pg_[w][d] = pg; pb_[w][d] = pb;
        __syncthreads();
        if (w == 0) {
            float dg = pg_[0][d] + pg_[1][d] + pg_[2][d] + pg_[3][d];
            float db = pb_[0][d] + pb_[1][d] + pb_[2][d] + pb_[3][d];
            float muv = ws[OFF_SUMX2 + d] * (1.f / 4096.f);
            float var = ws[OFF_SSQX2 + d] * (1.f / 4096.f) - muv * muv;
            scl[d] = (1.f + dg) * rsqrtf(var + 1e-5f);
            bta[d] = db; mu[d] = muv;
        }
        __syncthreads();
        float wk0 = Wk[d * 2 + 0], wk1 = Wk[d * 2 + 1];
        float wv0 = Wv[d * 2 + 0], wv1 = Wv[d * 2 + 1];
        float4* kvo = (float4*)(ws + OFF_KV);
        #pragma unroll
        for (int r = 0; r < 4; ++r) {
            int row = b * 16 + w * 4 + r;
            float x = x2[row * 64 + d];
            float n2 = wred64(x * x);
            float y = x * (1.f / fmaxf(sqrtf(n2), 1e-12f));            // y2 row
            float vv = fmaf(scl[d], x - mu[d], bta[d]);                // v2_0
            float nv = wred64(vv * vv);
            float vn = vv * (1.f / fmaxf(sqrtf(nv), 1e-12f));          // v2n
            float k0 = wred64(y * wk0),  k1 = wred64(y * wk1);
            float v0 = wred64(vn * wv0), v1 = wred64(vn * wv1);
            if (d == 0) kvo[row] = make_float4(k0, k1, v0, v1);
        }
    } else {
        float wq0 = Wq[d * 2 + 0], wq1 = Wq[d * 2 + 1];
        #pragma unroll
        for (int r = 0; r < 4; ++r) {
            int row = (b - 256) * 16 + w * 4 + r;
            float x = x1[row * 64 + d];
            float n2 = wred64(x * x);
            float y = x * (1.f / fmaxf(sqrtf(n2), 1e-12f));            // y1 row
            float q0 = wred64(y * wq0), q1 = wred64(y * wq1);
            if (d == 0) { ws[OFF_Q + row] = q0; ws[OFF_Q + 4096 + row] = q1; }
        }
    }
}

// K3: attention + output, no atomics. 512 blocks x 256 threads; block owns 8 s-rows,
// threads slice over t (16 coalesced float4 kv each), accumulate 8s x 2h in registers,
// wave shuffle-reduce + LDS cross-wave reduce, then sigmoid(o@Wo+bo) written directly.
__global__ __launch_bounds__(256) void k_attn_out(const float* __restrict__ ws,
                                                  const float* __restrict__ Wk,
                                                  const float* __restrict__ Wo,
                                                  const float* __restrict__ bo,
                                                  float* __restrict__ out) {
    int b = blockIdx.x, tid = threadIdx.x;
    int w = tid >> 6, lane = tid & 63;
    __shared__ float kb[2];
    __shared__ float qsh[2][8];
    if (w == 0) {   // ||Wk col|| bounds (analytic softmax shift; exps end up in [-2m,0])
        float c0 = Wk[lane * 2 + 0], c1 = Wk[lane * 2 + 1];
        float s0 = wred64(c0 * c0), s1 = wred64(c1 * c1);
        if (lane == 0) { kb[0] = sqrtf(s0); kb[1] = sqrtf(s1); }
    }
    if (tid >= 64 && tid < 72) {  // wave1 loads this block's 8 q-pairs
        int si = tid - 64;
        qsh[0][si] = ws[OFF_Q + b * 8 + si];
        qsh[1][si] = ws[OFF_Q + 4096 + b * 8 + si];
    }
    __syncthreads();
    float q0r[8], q1r[8], m0r[8], m1r[8];
    #pragma unroll
    for (int si = 0; si < 8; ++si) {   // pre-scale by log2(e): exp(x) = exp2(x*LOG2E)
        q0r[si] = qsh[0][si] * LOG2E;
        q1r[si] = qsh[1][si] * LOG2E;
        m0r[si] = fabsf(q0r[si]) * kb[0];
        m1r[si] = fabsf(q1r[si]) * kb[1];
    }
    float n0[8], d0[8], n1[8], d1[8];
    #pragma unroll
    for (int si = 0; si < 8; ++si) { n0[si] = 0.f; d0[si] = 0.f; n1[si] = 0.f; d1[si] = 0.f; }
    const float4* kvg = (const float4*)(ws + OFF_KV);
    for (int i = 0; i < 16; ++i) {
        float4 t = kvg[i * 256 + tid];
        #pragma unroll
        for (int si = 0; si < 8; ++si) {
            float e0 = exp2f(fmaf(q0r[si], t.x, -m0r[si]));
            n0[si] = fmaf(e0, t.z, n0[si]); d0[si] += e0;
            float e1 = exp2f(fmaf(q1r[si], t.y, -m1r[si]));
            n1[si] = fmaf(e1, t.w, n1[si]); d1[si] += e1;
        }
    }
    #pragma unroll
    for (int si = 0; si < 8; ++si) {
        n0[si] = wred64(n0[si]); d0[si] = wred64(d0[si]);
        n1[si] = wred64(n1[si]); d1[si] = wred64(d1[si]);
    }
    __shared__ float red[4][32];
    if (lane == 0) {
        #pragma unroll
        for (int si = 0; si < 8; ++si) {
            red[w][si]      = n0[si];
            red[w][8 + si]  = d0[si];
            red[w][16 + si] = n1[si];
            red[w][24 + si] = d1[si];
        }
    }
    __syncthreads();
    __shared__ float fin[32];
    if (tid < 32) fin[tid] = red[0][tid] + red[1][tid] + red[2][tid] + red[3][tid];
    __syncthreads();
    if (tid < 8) {
        float o0 = fin[tid]      / fin[8 + tid];
        float o1 = fin[16 + tid] / fin[24 + tid];
        float z0 = fmaf(o0, Wo[0], fmaf(o1, Wo[2], bo[0]));
        float z1 = fmaf(o0, Wo[1], fmaf(o1, Wo[3], bo[1]));
        int s = b * 8 + tid;
        out[s * 2 + 0] = 1.f / (1.f + __expf(-z0));
        out[s * 2 + 1] = 1.f / (1.f + __expf(-z1));
    }
}

extern "C" void kernel_launch(void* const* d_in, const int* in_sizes, int n_in,
                              void* d_out, int out_size, void* d_ws, size_t ws_size,
                              hipStream_t stream) {
    const float* x1  = (const float*)d_in[0];
    const float* x2  = (const float*)d_in[1];
    const float* Wq  = (const float*)d_in[2];
    const float* Wk  = (const float*)d_in[3];
    const float* Wv  = (const float*)d_in[4];
    const float* Wo  = (const float*)d_in[5];
    const float* bo  = (const float*)d_in[6];
    const float* Wg1 = (const float*)d_in[7];
    const float* Wg2 = (const float*)d_in[8];
    const float* Wb1 = (const float*)d_in[9];
    const float* Wb2 = (const float*)d_in[10];
    float* ws  = (float*)d_ws;
    float* out = (float*)d_out;

    // Zero only the 192-float atomic accumulation region (ws poisoned 0xAA).
    hipMemsetAsync(d_ws, 0, 192 * 4, stream);

    k_colred<<<256, 256, 0, stream>>>(x1, x2, ws);
    k_prep_proj<<<512, 256, 0, stream>>>(x1, x2, Wq, Wk, Wv, Wg1, Wg2, Wb1, Wb2, ws);
    k_attn_out<<<512, 256, 0, stream>>>(ws, Wk, Wo, bo, out);
}